// Round 10
// baseline (300.227 us; speedup 1.0000x reference)
//
#include <hip/hip_runtime.h>
#include <hip/hip_bf16.h>

typedef __attribute__((ext_vector_type(8))) short short8;
typedef __attribute__((ext_vector_type(4))) int i32x4;

#define HW     3136      // 56*56
#define M_TOT  200704    // 64*3136
#define NITER  9         // K=1152 / BK=128 (one 3x3 tap per iter)
#define NBLK   1568      // conv grid = M_TOT/128

__device__ __forceinline__ void gload_lds16(const void* g, void* l) {
    __builtin_amdgcn_global_load_lds(
        (const __attribute__((address_space(1))) void*)g,
        (__attribute__((address_space(3))) void*)l, 16, 0, 0);
}

// ---------------- weight prep ----------------
// wswzA layout (BK=128, i8): byte i = t*16384 + ks*8192 + f*1024 + l*16 + e
//   t = tap 0..8; cout = f*16 + (l&15); cin = ks*64 + (l>>4)*16 + e
__global__ __launch_bounds__(256) void wsign_kernel(const float* __restrict__ w1,
                                                    const float* __restrict__ w2,
                                                    char* __restrict__ ws1,
                                                    char* __restrict__ ws2) {
    int i = blockIdx.x * 256 + threadIdx.x;   // < 294912
    const float* w = w1;
    char* wsz = ws1;
    if (i >= 147456) { i -= 147456; w = w2; wsz = ws2; }
    int e = i & 15, l = (i >> 4) & 63, f = (i >> 10) & 7, ks = (i >> 13) & 1, t = i >> 14;
    int cout = f * 16 + (l & 15);
    int cin = ks * 64 + (l >> 4) * 16 + e;
    float v = w[(cout * 128 + cin) * 9 + t];
    wsz[i] = v > 0.f ? (char)1 : (v < 0.f ? (char)-1 : (char)0);
}

__global__ __launch_bounds__(256) void wscale_kernel(const float* __restrict__ w1,
                                                     const float* __restrict__ w2,
                                                     float* __restrict__ scale1,
                                                     float* __restrict__ scale2) {
    int o = blockIdx.x;                 // 256: 0..127 -> w1, 128..255 -> w2
    const float* w = w1;
    float* scale = scale1;
    if (o >= 128) { o -= 128; w = w2; scale = scale2; }
    int t = threadIdx.x;
    float s = 0.f;
    for (int i = t; i < 1152; i += 256) s += fabsf(w[o * 1152 + i]);
    __shared__ float r1[256];
    r1[t] = s; __syncthreads();
    for (int off = 128; off > 0; off >>= 1) {
        if (t < off) r1[t] += r1[t + off];
        __syncthreads();
    }
    if (t == 0) scale[o] = r1[0] * (1.f / 1152.f);
}

// ---------------- BN1 stats ----------------
__global__ __launch_bounds__(256) void stats_nchw_kernel(const float* __restrict__ x,
                                                         float* __restrict__ psum,
                                                         float* __restrict__ psq) {
    int bid = blockIdx.x;            // 8192: n = bid>>7, c = bid&127
    int n = bid >> 7, c = bid & 127;
    const float* p = x + (n * 128 + c) * HW;
    int t = threadIdx.x;
    float s = 0.f, q = 0.f;
    for (int i = t; i < HW; i += 256) { float v = p[i]; s += v; q += v * v; }
    __shared__ float r1[256], r2[256];
    r1[t] = s; r2[t] = q; __syncthreads();
    for (int off = 128; off > 0; off >>= 1) {
        if (t < off) { r1[t] += r1[t + off]; r2[t] += r2[t + off]; }
        __syncthreads();
    }
    if (t == 0) { psum[c * 64 + n] = r1[0]; psq[c * 64 + n] = r2[0]; }
}

__global__ void finalize_kernel(const float* __restrict__ psum, const float* __restrict__ psq,
                                int P, float* __restrict__ mean, float* __restrict__ rstd) {
    int c = threadIdx.x;
    if (c >= 128) return;
    float s = 0.f, q = 0.f;
    for (int j = 0; j < P; ++j) { s += psum[c * P + j]; q += psq[c * P + j]; }
    const float invN = 1.f / 200704.f;
    float m = s * invN;
    float var = q * invN - m * m;
    mean[c] = m;
    rstd[c] = 1.f / sqrtf(var + 1e-5f);
}

// reduce per-conv-block partials: psumB[c*NBLK + blk]
__global__ __launch_bounds__(256) void finalizeB_kernel(const float* __restrict__ psumB,
                                                        const float* __restrict__ psqB,
                                                        float* __restrict__ mean,
                                                        float* __restrict__ rstd) {
    int c = blockIdx.x, t = threadIdx.x;
    float s = 0.f, q = 0.f;
    for (int j = t; j < NBLK; j += 256) { s += psumB[c * NBLK + j]; q += psqB[c * NBLK + j]; }
    __shared__ float r1[256], r2[256];
    r1[t] = s; r2[t] = q; __syncthreads();
    for (int off = 128; off > 0; off >>= 1) {
        if (t < off) { r1[t] += r1[t + off]; r2[t] += r2[t + off]; }
        __syncthreads();
    }
    if (t == 0) {
        const float invN = 1.f / 200704.f;
        float m = r1[0] * invN;
        float var = r2[0] * invN - m * m;
        mean[c] = m;
        rstd[c] = 1.f / sqrtf(var + 1e-5f);
    }
}

// ---------------- normalize + sign -> padded NHWC i8 ----------------
// apad8: [n][h'][w'][c], 64x58x58x128 char, zero border, values {-1,0,1}
__global__ __launch_bounds__(256) void act1_kernel(const float* __restrict__ x,
        const float* __restrict__ mean, const float* __restrict__ rstd,
        const float* __restrict__ g, const float* __restrict__ b,
        char* __restrict__ apad) {
    __shared__ float row[128 * 57];
    int blk = blockIdx.x;                 // 64*58
    int n = blk / 58, hp = blk - n * 58;
    char* o = apad + (n * 58 + hp) * 58 * 128;
    int t = threadIdx.x;
    if (hp == 0 || hp == 57) {
        for (int i4 = t; i4 < 58 * 32; i4 += 256)
            *(char4*)(o + i4 * 4) = make_char4(0, 0, 0, 0);
        return;
    }
    const float* src = x + n * (128 * HW) + (hp - 1) * 56;
    for (int i = t; i < 128 * 56; i += 256) {
        int c = i / 56, w = i - c * 56;
        row[c * 57 + w] = src[c * HW + w];
    }
    __syncthreads();
    for (int i4 = t; i4 < 58 * 32; i4 += 256) {       // char4 per thread
        int wp = i4 >> 5;
        int c0 = (i4 & 31) * 4;
        char q[4] = {0, 0, 0, 0};
        if (wp >= 1 && wp <= 56) {
#pragma unroll
            for (int k = 0; k < 4; ++k) {
                int c = c0 + k;
                float xn = (row[c * 57 + wp - 1] - mean[c]) * rstd[c] * g[c] + b[c];
                q[k] = xn > 0.f ? 1 : (xn < 0.f ? -1 : 0);
            }
        }
        *(char4*)(o + wp * 128 + c0) = make_char4(q[0], q[1], q[2], q[3]);
    }
}

// act2: input is raw int16 conv1 accumulators [c][m]; apply scale1+prelu then BN2-sign
__global__ __launch_bounds__(256) void act2_kernel(const short* __restrict__ p1,
        const float* __restrict__ scale1, const float* __restrict__ a1ptr,
        const float* __restrict__ mean, const float* __restrict__ rstd,
        const float* __restrict__ g, const float* __restrict__ b,
        char* __restrict__ apad) {
    __shared__ float row[128 * 57];
    int blk = blockIdx.x;
    int n = blk / 58, hp = blk - n * 58;
    char* o = apad + (n * 58 + hp) * 58 * 128;
    int t = threadIdx.x;
    if (hp == 0 || hp == 57) {
        for (int i4 = t; i4 < 58 * 32; i4 += 256)
            *(char4*)(o + i4 * 4) = make_char4(0, 0, 0, 0);
        return;
    }
    float a1 = a1ptr[0];
    const short* src = p1 + n * HW + (hp - 1) * 56;   // + c*M_TOT + w
    for (int i = t; i < 128 * 56; i += 256) {
        int c = i / 56, w = i - c * 56;
        float v = scale1[c] * (float)src[(size_t)c * M_TOT + w];
        row[c * 57 + w] = v >= 0.f ? v : a1 * v;      // prelu1
    }
    __syncthreads();
    for (int i4 = t; i4 < 58 * 32; i4 += 256) {
        int wp = i4 >> 5;
        int c0 = (i4 & 31) * 4;
        char q[4] = {0, 0, 0, 0};
        if (wp >= 1 && wp <= 56) {
#pragma unroll
            for (int k = 0; k < 4; ++k) {
                int c = c0 + k;
                float xn = (row[c * 57 + wp - 1] - mean[c]) * rstd[c] * g[c] + b[c];
                q[k] = xn > 0.f ? 1 : (xn < 0.f ? -1 : 0);
            }
        }
        *(char4*)(o + wp * 128 + c0) = make_char4(q[0], q[1], q[2], q[3]);
    }
}

// ---------------- implicit-GEMM binary conv, i8 MFMA, BK=128 (one tap/iter) ----------------
// 128cout x 128m tile, 512 threads (8 waves: wr=wid>>2 cout-half, wc=wid&3 m-quarter of 32).
// B LDS is m-major [128][128] with XOR swizzle (byte ^= (m&7)<<4): staging is FULL-LINE
// coalesced (8 lanes x 16B = one 128B row per m; 8 full lines per gload), reads 2-way free.
// A LDS fragment-order identity. 3 buffers x 32KB, counted vmcnt (never 0 mid-loop),
// raw s_barrier, setprio around MFMA cluster.
// obuf[cout][m] = raw int16 accumulator (pre-scale, pre-prelu) — exact
// fused BN stats over prelu(scale*acc): psumB/psqB[c*NBLK+blk]
__global__ __launch_bounds__(512, 2) void conv_kernel(
        const char* __restrict__ apad,
        const char* __restrict__ wswz,
        const float* __restrict__ scale,
        const float* __restrict__ aptr,
        short* __restrict__ obuf,
        float* __restrict__ psumB,
        float* __restrict__ psqB) {
    // per buffer: A 16KB (frag order, [ks][f][lane][16]) then B 16KB (m-major swizzled)
    __shared__ __align__(1024) char lds[3][32768];

    const int tid = threadIdx.x;     // 0..511
    const int lane = tid & 63;
    const int wid = tid >> 6;        // 0..7
    const int l15 = lane & 15;
    const int lq = lane >> 4;
    const int wr = wid >> 2;         // cout half 0..1
    const int wc = wid & 3;          // m quarter 0..3

    int bid = blockIdx.x;
    int mblk = (bid & 7) * 196 + (bid >> 3);   // XCD-contiguous (1568 = 8*196)
    const int m0 = mblk * 128;

    // B staging: gload j stages LDS bytes [16384 + j*8192 + tid*16 .. +16)
    //   -> m_loc = j*64 + (tid>>3), kb = (tid&7)*16; content cin = kb ^ ((m_loc&7)<<4)
    //   source = rowbase(m0+m_loc) + toff + (kb ^ swz)  — 8 lanes cover one full 128B row
    const char* bsrc[2];
    {
        int kb = (tid & 7) * 16;
#pragma unroll
        for (int j = 0; j < 2; ++j) {
            int mloc = j * 64 + (tid >> 3);
            int m = m0 + mloc;
            int n = m / HW;
            int r = m - n * HW;
            int h = r / 56;
            int w = r - h * 56;
            bsrc[j] = apad + (((n * 58 + h) * 58 + w) * 128 + (kb ^ ((mloc & 7) << 4)));
        }
    }

    i32x4 acc[4][2];
#pragma unroll
    for (int i = 0; i < 4; ++i)
#pragma unroll
        for (int j = 0; j < 2; ++j)
            acc[i][j] = (i32x4){0, 0, 0, 0};

    // ---- stage tap t into buffer buf (4 gload_lds per thread = 4 vmcnt ticks) ----
    auto stage = [&](int t, int buf) {
        int dh = t / 3;
        int dw = t - dh * 3;
        int toff = (dh * 58 + dw) * 128;
        const char* wsrc = wswz + t * 16384 + tid * 16;
        gload_lds16(wsrc,        lds[buf] + wid * 1024);                  // A ks=0
        gload_lds16(wsrc + 8192, lds[buf] + 8192 + wid * 1024);           // A ks=1
        gload_lds16(bsrc[0] + toff, lds[buf] + 16384 + wid * 1024);       // B m 0-63
        gload_lds16(bsrc[1] + toff, lds[buf] + 24576 + wid * 1024);       // B m 64-127
    };

    stage(0, 0);
    stage(1, 1);          // 8 loads/thread in flight

    for (int t = 0; t < NITER; ++t) {
        // wait for stage(t) only (counted, in-order vmcnt), keep stage(t+1) flying
        if (t + 1 < NITER) asm volatile("s_waitcnt vmcnt(4)" ::: "memory");
        else               asm volatile("s_waitcnt vmcnt(0)" ::: "memory");
        __builtin_amdgcn_s_barrier();
        __builtin_amdgcn_sched_barrier(0);   // pin: no ds_read hoisting above barrier
        if (t + 2 < NITER) stage(t + 2, (t + 2) % 3);

        const char* bufp = lds[t % 3];
        i32x4 af[4][2], bf[2][2];
#pragma unroll
        for (int ks = 0; ks < 2; ++ks) {
#pragma unroll
            for (int ci = 0; ci < 4; ++ci)
                af[ci][ks] = *(const i32x4*)(bufp + ks * 8192 + (wr * 4 + ci) * 1024 + lane * 16);
#pragma unroll
            for (int mi = 0; mi < 2; ++mi) {
                int mloc = wc * 32 + mi * 16 + l15;
                int kbyte = (ks * 64 + lq * 16) ^ ((mloc & 7) << 4);
                bf[mi][ks] = *(const i32x4*)(bufp + 16384 + mloc * 128 + kbyte);
            }
        }
        __builtin_amdgcn_s_setprio(1);
#pragma unroll
        for (int ci = 0; ci < 4; ++ci)
#pragma unroll
            for (int mi = 0; mi < 2; ++mi)
#pragma unroll
                for (int ks = 0; ks < 2; ++ks)
                    acc[ci][mi] = __builtin_amdgcn_mfma_i32_16x16x64_i8(
                        af[ci][ks], bf[mi][ks], acc[ci][mi], 0, 0, 0);
        __builtin_amdgcn_s_setprio(0);
    }

    // ---- epilogue: store raw int16 + fused per-channel stats of prelu(scale*acc) ----
    // partS/partQ reuse lds[0] (last read at t=6; concurrent waves are in t=8 on lds[2])
    float alpha = aptr[0];
    float* partS = (float*)&lds[0][0];     // [4 m-quarter][128 cout]
    float* partQ = (float*)&lds[0][2048];
#pragma unroll
    for (int ci = 0; ci < 4; ++ci) {
        int cb = wr * 64 + ci * 16 + lq * 4;
        int mb = m0 + wc * 32 + l15;
#pragma unroll
        for (int r = 0; r < 4; ++r) {
            float sc = scale[cb + r];
            short* op = obuf + (size_t)(cb + r) * M_TOT + mb;
            float s = 0.f, q = 0.f;
#pragma unroll
            for (int mi = 0; mi < 2; ++mi) {
                int iv = acc[ci][mi][r];
                float v = (float)iv * sc;
                float pv = v >= 0.f ? v : alpha * v;
                op[mi * 16] = (short)iv;
                s += pv; q += pv * pv;
            }
#pragma unroll
            for (int msk = 1; msk <= 8; msk <<= 1) {
                s += __shfl_xor(s, msk, 64);
                q += __shfl_xor(q, msk, 64);
            }
            if (l15 == 0) { partS[wc * 128 + cb + r] = s; partQ[wc * 128 + cb + r] = q; }
        }
    }
    __syncthreads();
    if (tid < 128) {
        psumB[tid * NBLK + bid] = partS[tid] + partS[128 + tid] + partS[256 + tid] + partS[384 + tid];
        psqB [tid * NBLK + bid] = partQ[tid] + partQ[128 + tid] + partQ[256 + tid] + partQ[384 + tid];
    }
}

// ---------------- final: scale2+prelu2 + BN3 + residual + prelu3 ----------------
__global__ __launch_bounds__(256) void final_kernel(const short* __restrict__ p2,
        const float* __restrict__ scale2, const float* __restrict__ a2ptr,
        const float* __restrict__ x,
        const float* __restrict__ mean, const float* __restrict__ rstd,
        const float* __restrict__ g, const float* __restrict__ b,
        const float* __restrict__ a3ptr, float* __restrict__ out) {
    int bid = blockIdx.x;               // 8192
    int n = bid >> 7, c = bid & 127;
    float sc = scale2[c], a2 = a2ptr[0];
    float m = mean[c], r = rstd[c], gg = g[c], bb = b[c], a3 = a3ptr[0];
    const short* pp = p2 + (size_t)c * M_TOT + n * HW;
    const float* xx = x + (n * 128 + c) * HW;
    float* oo = out + (n * 128 + c) * HW;
    int t = threadIdx.x;
    for (int i8 = t; i8 < 392; i8 += 256) {     // 3136 = 392*8
        short8 v = *(const short8*)(pp + i8 * 8);
        float4 x0 = *(const float4*)(xx + i8 * 8);
        float4 x1 = *(const float4*)(xx + i8 * 8 + 4);
        float o[8];
#pragma unroll
        for (int k = 0; k < 8; ++k) {
            float pv = (float)v[k] * sc;
            pv = pv >= 0.f ? pv : a2 * pv;      // prelu2
            float xv = (k < 4) ? ((const float*)&x0)[k] : ((const float*)&x1)[k - 4];
            float val = (pv - m) * r * gg + bb + xv;
            o[k] = val >= 0.f ? val : a3 * val; // prelu3
        }
        *(float4*)(oo + i8 * 8)     = make_float4(o[0], o[1], o[2], o[3]);
        *(float4*)(oo + i8 * 8 + 4) = make_float4(o[4], o[5], o[6], o[7]);
    }
}

extern "C" void kernel_launch(void* const* d_in, const int* in_sizes, int n_in,
                              void* d_out, int out_size, void* d_ws, size_t ws_size,
                              hipStream_t stream) {
    const float* x  = (const float*)d_in[0];
    const float* g1 = (const float*)d_in[1];
    const float* b1 = (const float*)d_in[2];
    const float* w1 = (const float*)d_in[3];
    const float* a1 = (const float*)d_in[4];
    const float* g2 = (const float*)d_in[5];
    const float* b2 = (const float*)d_in[6];
    const float* w2 = (const float*)d_in[7];
    const float* a2 = (const float*)d_in[8];
    const float* g3 = (const float*)d_in[9];
    const float* b3 = (const float*)d_in[10];
    const float* a3 = (const float*)d_in[11];
    float* out = (float*)d_out;
    char* ws = (char*)d_ws;

    // Workspace map — end offsets computed as start + exact size:
    //   psum   4,096   + 32,768   = 36,864
    //   psq    36,864  + 32,768   = 69,632
    //   psumB  69,632  + 802,816  = 872,448      (128*1568*4)
    //   psqB   872,448 + 802,816  = 1,675,264
    //   wswz1  1,675,264 + 147,456 = 1,822,720
    //   wswz2  1,822,720 + 147,456 = 1,970,176
    //   apad8  1,970,176 + 27,557,888 = 29,528,064   (64*58*58*128 bytes)
    //   buf2s  29,528,064 + 51,380,224 = 80,908,288  (2*128*200704)
    float* scale1 = (float*)(ws);
    float* scale2 = (float*)(ws + 512);
    float* mean1  = (float*)(ws + 1024);
    float* rstd1  = (float*)(ws + 1536);
    float* mean2  = (float*)(ws + 2048);
    float* rstd2  = (float*)(ws + 2560);
    float* mean3  = (float*)(ws + 3072);
    float* rstd3  = (float*)(ws + 3584);
    float* psum   = (float*)(ws + 4096);
    float* psq    = (float*)(ws + 36864);
    float* psumB  = (float*)(ws + 69632);
    float* psqB   = (float*)(ws + 872448);
    char* wswz1   = (char*)(ws + 1675264);
    char* wswz2   = (char*)(ws + 1822720);
    char* apad8   = (char*)(ws + 1970176);
    short* buf2s  = (short*)(ws + 29528064);
    short* buf1s  = (short*)out;              // alias d_out (51.4 of 103 MB)

    wscale_kernel<<<256, 256, 0, stream>>>(w1, w2, scale1, scale2);
    wsign_kernel<<<1152, 256, 0, stream>>>(w1, w2, wswz1, wswz2);

    stats_nchw_kernel<<<8192, 256, 0, stream>>>(x, psum, psq);
    finalize_kernel<<<1, 128, 0, stream>>>(psum, psq, 64, mean1, rstd1);
    act1_kernel<<<3712, 256, 0, stream>>>(x, mean1, rstd1, g1, b1, apad8);
    conv_kernel<<<NBLK, 512, 0, stream>>>(apad8, wswz1, scale1, a1, buf1s, psumB, psqB);

    finalizeB_kernel<<<128, 256, 0, stream>>>(psumB, psqB, mean2, rstd2);
    act2_kernel<<<3712, 256, 0, stream>>>(buf1s, scale1, a1, mean2, rstd2, g2, b2, apad8);
    conv_kernel<<<NBLK, 512, 0, stream>>>(apad8, wswz2, scale2, a2, buf2s, psumB, psqB);

    finalizeB_kernel<<<128, 256, 0, stream>>>(psumB, psqB, mean3, rstd3);
    final_kernel<<<8192, 256, 0, stream>>>(buf2s, scale2, a2, x, mean3, rstd3, g3, b3, a3, out);
}